// Round 7
// baseline (315.407 us; speedup 1.0000x reference)
//
#include <hip/hip_runtime.h>

// GAT-style graph conv: B=2, C=128, N=10000, K=16, fp32 in/out.
// SINGLE fused kernel with a manual device-scope barrier (no cooperative
// launch). Phase 1 (MFMA gemm): wht = W*x (bf16 rows), si/sj = a.wh.
// Phase 2 (gather): e=leaky(si[i]+sj[j]); A=softmax_k; out=sum_k A*wht[j].
// XCD pinning both phases: batch = (bk%8)>>2 -> batch b lives on XCDs
// b*4..b*4+3; its 2.56MB wht fits that group's L2s -> gathers are L2 hits.
// Residency (deadlock-free barrier): grid 632 blocks, bounds(256,3) ->
// capacity 256CU*3 = 768 >= 632; LDS 21KB*3 = 63KB <= 160KB.
// R7: R6's barrier had ALL 160k threads spinning on the flag array ->
// 220us of cross-XCD atomic contention (VALUBusy 2.2%, Occ 28%). Replaced
// with two-level barrier: arrive flags -> master block sweeps (wave 0,
// 10 flags/lane) -> single GO word -> 1 poller thread per block, long
// sleeps. Poller count ~250x down, poll rate ~16x down. Compute phases
// byte-identical to R6 (numerically verified, absmax 0.0039).

#define BB 2
#define CC 128
#define NN 10000
#define KK 16
#define TNG 32     // nodes per gemm tile
#define TNA 16     // nodes per gather slot
#define LSTR 136   // xs row stride in ushorts (272 B -> b128-aligned rows)
#define OPAD 132   // outT2 row stride in floats
#define NBLK 632   // 79*8 blocks; 316 groups/batch
#define GPBATCH 316
#define TPB 313    // gemm tiles per batch
#define SPB 625    // gather slots per batch
#define MAGIC 0x9E3779B9u

typedef unsigned int uint32;
typedef __attribute__((ext_vector_type(8))) short short8;   // bf16 A/B frag
typedef __attribute__((ext_vector_type(4))) float floatx4;  // f32 C/D frag

__device__ __forceinline__ uint32 bf16pair(float lo, float hi) {
  uint32 ulo = __float_as_uint(lo);
  uint32 uhi = __float_as_uint(hi);
  ulo += 0x7fffu + ((ulo >> 16) & 1u);
  uhi += 0x7fffu + ((uhi >> 16) & 1u);
  return (ulo >> 16) | (uhi & 0xffff0000u);
}

__device__ __forceinline__ void nap(int sweeps) {
  for (int z = 0; z < sweeps; ++z) __builtin_amdgcn_s_sleep(2);
}

__global__ __launch_bounds__(256, 3) void gat_fused_mb(
    const float* __restrict__ x,    // [B,C,N]
    const int* __restrict__ ei,     // [2,B,N,K]
    const float* __restrict__ W,    // [C,C] row-major
    const float* __restrict__ a,    // [2C]
    uint32* __restrict__ wht,       // [B,N,C/2] bf16 pairs (ws)
    float* __restrict__ si,         // [B,N] (ws)
    float* __restrict__ sj,         // [B,N] (ws)
    uint32* flags,                  // [NBLK+1] (ws, poison-reset each replay)
    float* __restrict__ out) {      // [B,C,N]
  __shared__ union {
    struct { unsigned short xs[TNG * LSTR]; float red[2][4][2][16]; } p1;    // 9728 B
    struct { float Am[2][TNA][KK]; int jd[2][TNA][KK];
             float outT2[2][TNA][OPAD]; } p2;                                 // 20992 B
  } sm;

  const int bk  = blockIdx.x;
  const int xcd = bk & 7;                       // presumed bid%8 XCD round-robin
  const int b   = xcd >> 2;                     // XCDs 0-3 -> b0, 4-7 -> b1
  const int g   = (bk >> 3) * 4 + (xcd & 3);    // 0..315 within batch
  const int t   = threadIdx.x;
  const bool have2 = (g + GPBATCH) < SPB;       // second gather slot valid

  // ================= Phase 1: GEMM (tile g of batch b) =================
  if (g < TPB) {
    const int n0   = g * TNG;
    const int w    = t >> 6;
    const int lane = t & 63;
    const int col  = lane & 15;
    const int q    = lane >> 4;

    {  // stage x tile -> node-major bf16
      const float* xb = x + (size_t)b * CC * NN;
      uint32* xd = (uint32*)sm.p1.xs;
#pragma unroll
      for (int i = 0; i < 8; ++i) {
        int e = t + i * 256;
        int n = e & 31, cpair = e >> 5;
        int c = cpair * 2, gn = n0 + n;
        float v0 = 0.f, v1 = 0.f;
        if (gn < NN) { v0 = xb[c * NN + gn]; v1 = xb[(c + 1) * NN + gn]; }
        xd[n * 68 + cpair] = bf16pair(v0, v1);
      }
    }

    short8 af[2][4];
#pragma unroll
    for (int ci = 0; ci < 2; ++ci) {
      const float* wr = W + (w * 32 + ci * 16 + col) * CC;
#pragma unroll
      for (int s = 0; s < 4; ++s) {
        float4 f0 = *(const float4*)(wr + s * 32 + q * 8);
        float4 f1 = *(const float4*)(wr + s * 32 + q * 8 + 4);
        union { uint32 u[4]; short8 v; } cv;
        cv.u[0] = bf16pair(f0.x, f0.y);
        cv.u[1] = bf16pair(f0.z, f0.w);
        cv.u[2] = bf16pair(f1.x, f1.y);
        cv.u[3] = bf16pair(f1.z, f1.w);
        af[ci][s] = cv.v;
      }
    }
    __syncthreads();

    floatx4 acc[2][2];
#pragma unroll
    for (int ci = 0; ci < 2; ++ci)
#pragma unroll
      for (int nj = 0; nj < 2; ++nj) acc[ci][nj] = (floatx4){0.f, 0.f, 0.f, 0.f};

#pragma unroll
    for (int s = 0; s < 4; ++s) {
      short8 bf[2];
#pragma unroll
      for (int nj = 0; nj < 2; ++nj)
        bf[nj] = *(const short8*)(sm.p1.xs + (nj * 16 + col) * LSTR + s * 32 + q * 8);
#pragma unroll
      for (int ci = 0; ci < 2; ++ci)
#pragma unroll
        for (int nj = 0; nj < 2; ++nj)
          acc[ci][nj] = __builtin_amdgcn_mfma_f32_16x16x32_bf16(af[ci][s], bf[nj], acc[ci][nj], 0, 0, 0);
    }

    float ar[2][4], aj4[2][4];
#pragma unroll
    for (int ci = 0; ci < 2; ++ci)
#pragma unroll
      for (int r = 0; r < 4; ++r) {
        int ch = w * 32 + ci * 16 + q * 4 + r;
        ar[ci][r]  = a[ch];
        aj4[ci][r] = a[CC + ch];
      }

#pragma unroll
    for (int nj = 0; nj < 2; ++nj) {
      int node = n0 + nj * 16 + col;
      float psi = 0.f, psj = 0.f;
#pragma unroll
      for (int ci = 0; ci < 2; ++ci) {
#pragma unroll
        for (int r = 0; r < 4; ++r) {
          psi = fmaf(ar[ci][r], acc[ci][nj][r], psi);
          psj = fmaf(aj4[ci][r], acc[ci][nj][r], psj);
        }
        if (node < NN) {
          uint2 pk;
          pk.x = bf16pair(acc[ci][nj][0], acc[ci][nj][1]);
          pk.y = bf16pair(acc[ci][nj][2], acc[ci][nj][3]);
          uint2* dst = (uint2*)(wht + ((size_t)(b * NN + node)) * (CC / 2) + w * 16 + ci * 8 + q * 2);
          *dst = pk;
        }
      }
      psi += __shfl_down(psi, 32);
      psi += __shfl_down(psi, 16);
      psj += __shfl_down(psj, 32);
      psj += __shfl_down(psj, 16);
      if (q == 0) { sm.p1.red[0][w][nj][col] = psi; sm.p1.red[1][w][nj][col] = psj; }
    }
    __syncthreads();

    if (t < TNG) {
      int gn = n0 + t;
      if (gn < NN) {
        int nj = t >> 4, cl = t & 15;
        float s1 = 0.f, s2 = 0.f;
#pragma unroll
        for (int ww = 0; ww < 4; ++ww) { s1 += sm.p1.red[0][ww][nj][cl]; s2 += sm.p1.red[1][ww][nj][cl]; }
        si[b * NN + gn] = s1;
        sj[b * NN + gn] = s2;
      }
    }
  }

  // ======== Two-level device barrier (release/acquire, agent scope) ========
  // Arrive: flags[bk]=MAGIC. Master (block 0, wave 0) sweeps all flags,
  // then sets GO=flags[NBLK]. Spinners: ONE thread per block polls GO.
  __threadfence();
  __syncthreads();
  if (t == 0)
    __hip_atomic_store(&flags[bk], MAGIC, __ATOMIC_RELEASE, __HIP_MEMORY_SCOPE_AGENT);

  if (bk == 0) {
    if (t < 64) {
      bool alldone = false;
      while (!alldone) {
        bool mine = true;
        for (int f = t; f < NBLK; f += 64)
          if (__hip_atomic_load(&flags[f], __ATOMIC_ACQUIRE, __HIP_MEMORY_SCOPE_AGENT) != MAGIC)
            mine = false;
        alldone = __all(mine);
        if (!alldone) nap(4);
      }
      if (t == 0)
        __hip_atomic_store(&flags[NBLK], MAGIC, __ATOMIC_RELEASE, __HIP_MEMORY_SCOPE_AGENT);
    }
  } else {
    if (t == 0) {
      while (__hip_atomic_load(&flags[NBLK], __ATOMIC_ACQUIRE, __HIP_MEMORY_SCOPE_AGENT) != MAGIC)
        nap(16);
    }
  }
  __syncthreads();
  __threadfence();

  // ================= Phase 2: gather, slots g and g+316 ====================
  const int* eij = ei + b * NN * KK;
  const int* eii = ei + (BB + b) * NN * KK;
  const float* sib = si + b * NN;
  const float* sjb = sj + b * NN;

  // Phase A: per slot, one edge per thread; softmax in-register (16-lane shfl).
  {
    int nn = t >> 4, k = t & 15;
#pragma unroll
    for (int sl = 0; sl < 2; ++sl) {
      if (sl && !have2) break;
      int gn = (g + sl * GPBATCH) * TNA + nn;   // <= 9999 by construction
      int jj = eij[gn * KK + k];
      int ii = eii[gn * KK + k];
      float v = sib[ii] + sjb[jj];
      float el = (v > 0.f) ? v : 0.2f * v;
      float mx = el;
#pragma unroll
      for (int d = 1; d < KK; d <<= 1) mx = fmaxf(mx, __shfl_xor(mx, d));
      float ex = __expf(el - mx);
      float ssum = ex;
#pragma unroll
      for (int d = 1; d < KK; d <<= 1) ssum += __shfl_xor(ssum, d);
      sm.p2.Am[sl][nn][k] = ex / ssum;
      sm.p2.jd[sl][nn][k] = jj;
    }
  }
  __syncthreads();

  // Phase C: lane owns node nn (per slot), channels c16*8..+7; paired slots
  // keep 16 uint4 loads in flight per pass.
  const int lane = t & 63;
  const int nw   = t >> 6;
  const int nn   = nw * 4 + (lane >> 4);
  const int c16  = lane & 15;
  const uint32 lo4 = (uint32)(c16 * 4);
  const uint32* whtb = wht + (size_t)b * NN * (CC / 2);

  uint32 rws[2][KK]; float wgt[2][KK];
#pragma unroll
  for (int sl = 0; sl < 2; ++sl) {
    if (sl && !have2) break;
    uint4 iv[4]; float4 wv[4];
#pragma unroll
    for (int gq = 0; gq < 4; ++gq) {
      iv[gq] = ((const uint4*)&sm.p2.jd[sl][nn][0])[gq];
      wv[gq] = ((const float4*)&sm.p2.Am[sl][nn][0])[gq];
    }
#pragma unroll
    for (int gq = 0; gq < 4; ++gq) {
      rws[sl][4 * gq + 0] = iv[gq].x; rws[sl][4 * gq + 1] = iv[gq].y;
      rws[sl][4 * gq + 2] = iv[gq].z; rws[sl][4 * gq + 3] = iv[gq].w;
      wgt[sl][4 * gq + 0] = wv[gq].x; wgt[sl][4 * gq + 1] = wv[gq].y;
      wgt[sl][4 * gq + 2] = wv[gq].z; wgt[sl][4 * gq + 3] = wv[gq].w;
    }
  }

  float accA[8], accB[8];
#pragma unroll
  for (int r = 0; r < 8; ++r) { accA[r] = 0.f; accB[r] = 0.f; }

#pragma unroll
  for (int half = 0; half < 2; ++half) {
    uint4 va[8], vb[8];
#pragma unroll
    for (int k = 0; k < 8; ++k)
      va[k] = *(const uint4*)(whtb + rws[0][half * 8 + k] * (uint32)(CC / 2) + lo4);
    if (have2) {
#pragma unroll
      for (int k = 0; k < 8; ++k)
        vb[k] = *(const uint4*)(whtb + rws[1][half * 8 + k] * (uint32)(CC / 2) + lo4);
    }
#pragma unroll
    for (int k = 0; k < 8; ++k) {
      float wk = wgt[0][half * 8 + k];
      uint32 dw[4] = {va[k].x, va[k].y, va[k].z, va[k].w};
#pragma unroll
      for (int d = 0; d < 4; ++d) {
        accA[2 * d]     = fmaf(wk, __uint_as_float(dw[d] << 16), accA[2 * d]);
        accA[2 * d + 1] = fmaf(wk, __uint_as_float(dw[d] & 0xffff0000u), accA[2 * d + 1]);
      }
    }
    if (have2) {
#pragma unroll
      for (int k = 0; k < 8; ++k) {
        float wk = wgt[1][half * 8 + k];
        uint32 dw[4] = {vb[k].x, vb[k].y, vb[k].z, vb[k].w};
#pragma unroll
        for (int d = 0; d < 4; ++d) {
          accB[2 * d]     = fmaf(wk, __uint_as_float(dw[d] << 16), accB[2 * d]);
          accB[2 * d + 1] = fmaf(wk, __uint_as_float(dw[d] & 0xffff0000u), accB[2 * d + 1]);
        }
      }
    }
  }

  {
    float* orow = &sm.p2.outT2[0][nn][c16 * 8];
    *(float4*)(orow)     = (float4){accA[0], accA[1], accA[2], accA[3]};
    *(float4*)(orow + 4) = (float4){accA[4], accA[5], accA[6], accA[7]};
    if (have2) {
      float* orow2 = &sm.p2.outT2[1][nn][c16 * 8];
      *(float4*)(orow2)     = (float4){accB[0], accB[1], accB[2], accB[3]};
      *(float4*)(orow2 + 4) = (float4){accB[4], accB[5], accB[6], accB[7]};
    }
  }
  __syncthreads();

  // Phase D: coalesced channel-major store, both slots.
  float* outb = out + (size_t)b * CC * NN;
#pragma unroll
  for (int sl = 0; sl < 2; ++sl) {
    if (sl && !have2) break;
    int n0o = (g + sl * GPBATCH) * TNA;
#pragma unroll
    for (int i = 0; i < 8; ++i) {
      int e = t + i * 256;
      int c = e >> 4, nd = e & 15;
      outb[c * NN + n0o + nd] = sm.p2.outT2[sl][nd][c];
    }
  }
}

extern "C" void kernel_launch(void* const* d_in, const int* in_sizes, int n_in,
                              void* d_out, int out_size, void* d_ws, size_t ws_size,
                              hipStream_t stream) {
  const float* x  = (const float*)d_in[0];   // [B,C,N,1]
  const int*   ei = (const int*)d_in[1];     // [2,B,N,K]
  const float* W  = (const float*)d_in[2];   // [C,C]
  const float* a  = (const float*)d_in[3];   // [2C]
  float* out = (float*)d_out;                // [B,C,N,1]

  uint32* wht   = (uint32*)d_ws;                              // 5.12 MB
  float*  si    = (float*)(wht + (size_t)BB * NN * (CC / 2)); // 80 KB
  float*  sj    = si + BB * NN;                               // 80 KB
  uint32* flags = (uint32*)(sj + BB * NN);                    // 2.5 KB (+GO)

  gat_fused_mb<<<dim3(NBLK), 256, 0, stream>>>(x, ei, W, a, wht, si, sj, flags, out);
}

// Round 8
// 87.771 us; speedup vs baseline: 3.5935x; 3.5935x over previous
//
#include <hip/hip_runtime.h>

// GAT-style graph conv: B=2, C=128, N=10000, K=16, fp32 in/out.
//   k1 (gemm, MFMA bf16): wht[b][n][c] = sum_c' W[c][c']*x[b][c'][n] (bf16 packed)
//               si[b][n] = a[0:C].wh[n], sj[b][n] = a[C:2C].wh[n]  (fp32, from acc)
//   k2 (gather): e = leaky(si[idx_i]+sj[idx_j]); A = softmax_k(e)
//               out[b][c][n] = sum_k A[n,k] * wht[b][idx_j[n,k]][c]
// Gather is XCD-pinned: batch = (blockIdx%8)>>2 so each XCD's L2 (4 MiB) only
// caches its batch's 2.56 MB of wht -> random row-gathers become L2 hits.
// R8: REVERT to the proven R4 two-kernel pipeline (86.78us). R6/R7 proved
// single-kernel fusion loses ~3x: device-scope fences on 8-XCD CDNA force
// serialized L2 writeback/invalidate (~250us for 632 blocks); the kernel
// boundary performs that flush once in hardware. Two dispatches are the
// cheapest device-wide barrier available on this part.

#define BB 2
#define CC 128
#define NN 10000
#define KK 16
#define TNG 32    // nodes per gemm block
#define TNA 16    // nodes per gather block
#define LSTR 136  // xs row stride in ushorts (272 B = 17*16 -> b128-aligned rows)
#define OPAD 132  // outT2 row stride in floats (528 B: 16B-aligned, 2-way banks)

typedef unsigned int uint32;
typedef __attribute__((ext_vector_type(8))) short short8;   // bf16 A/B frag
typedef __attribute__((ext_vector_type(4))) float floatx4;  // f32 C/D frag

__device__ __forceinline__ uint32 bf16pair(float lo, float hi) {
  // round-to-nearest-even bf16, packed (lo low 16, hi high 16)
  uint32 ulo = __float_as_uint(lo);
  uint32 uhi = __float_as_uint(hi);
  ulo += 0x7fffu + ((ulo >> 16) & 1u);
  uhi += 0x7fffu + ((uhi >> 16) & 1u);
  return (ulo >> 16) | (uhi & 0xffff0000u);
}

// ---------------- GEMM via MFMA 16x16x32 bf16, register-resident W frags ----
// Block: 256 thr (4 waves). Wave w: channels w*32..+31 x 32 nodes.
__global__ __launch_bounds__(256) void gat_gemm(
    const float* __restrict__ x,    // [B,C,N]
    const float* __restrict__ W,    // [C,C] row-major W[o][c]
    const float* __restrict__ a,    // [2C]
    uint32* __restrict__ wht,       // [B,N,C/2] bf16 pairs
    float* __restrict__ si,         // [B,N]
    float* __restrict__ sj) {       // [B,N]
  __shared__ unsigned short xs[TNG * LSTR];   // 8704 B, node-major bf16 x tile
  __shared__ float red[2][4][2][16];          // 1 KB si/sj partials

  const int b    = blockIdx.y;
  const int n0   = blockIdx.x * TNG;
  const int t    = threadIdx.x;
  const int w    = t >> 6;       // wave -> channel group w*32
  const int lane = t & 63;
  const int col  = lane & 15;    // MFMA col (node) / A row (channel)
  const int q    = lane >> 4;    // quad -> k offset q*8

  // --- Stage x tile, transpose to node-major bf16 (coalesced 128B row reads) ---
  {
    const float* xb = x + (size_t)b * CC * NN;
    uint32* xd = (uint32*)xs;
#pragma unroll
    for (int i = 0; i < 8; ++i) {
      int e = t + i * 256;
      int n = e & 31, cp = e >> 5;     // cp = channel pair 0..63
      int c = cp * 2, gn = n0 + n;
      float v0 = 0.f, v1 = 0.f;
      if (gn < NN) { v0 = xb[c * NN + gn]; v1 = xb[(c + 1) * NN + gn]; }
      xd[n * 68 + cp] = bf16pair(v0, v1);
    }
  }

  // --- A-fragments straight from global fp32 W -> bf16 registers (no LDS) ---
  short8 af[2][4];
#pragma unroll
  for (int ci = 0; ci < 2; ++ci) {
    const float* wr = W + (w * 32 + ci * 16 + col) * CC;
#pragma unroll
    for (int s = 0; s < 4; ++s) {
      float4 f0 = *(const float4*)(wr + s * 32 + q * 8);
      float4 f1 = *(const float4*)(wr + s * 32 + q * 8 + 4);
      union { uint32 u[4]; short8 v; } cv;
      cv.u[0] = bf16pair(f0.x, f0.y);
      cv.u[1] = bf16pair(f0.z, f0.w);
      cv.u[2] = bf16pair(f1.x, f1.y);
      cv.u[3] = bf16pair(f1.z, f1.w);
      af[ci][s] = cv.v;
    }
  }
  __syncthreads();

  floatx4 acc[2][2];
#pragma unroll
  for (int ci = 0; ci < 2; ++ci)
#pragma unroll
    for (int nj = 0; nj < 2; ++nj) acc[ci][nj] = (floatx4){0.f, 0.f, 0.f, 0.f};

#pragma unroll
  for (int s = 0; s < 4; ++s) {
    short8 bf[2];
#pragma unroll
    for (int nj = 0; nj < 2; ++nj)
      bf[nj] = *(const short8*)(xs + (nj * 16 + col) * LSTR + s * 32 + q * 8);
#pragma unroll
    for (int ci = 0; ci < 2; ++ci)
#pragma unroll
      for (int nj = 0; nj < 2; ++nj)
        acc[ci][nj] = __builtin_amdgcn_mfma_f32_16x16x32_bf16(af[ci][s], bf[nj], acc[ci][nj], 0, 0, 0);
  }

  // --- Epilogue: channel = w*32+ci*16+q*4+r, node = n0+nj*16+col ---
  float ar[2][4], aj4[2][4];
#pragma unroll
  for (int ci = 0; ci < 2; ++ci)
#pragma unroll
    for (int r = 0; r < 4; ++r) {
      int ch = w * 32 + ci * 16 + q * 4 + r;
      ar[ci][r]  = a[ch];
      aj4[ci][r] = a[CC + ch];
    }

#pragma unroll
  for (int nj = 0; nj < 2; ++nj) {
    int node = n0 + nj * 16 + col;
    float psi = 0.f, psj = 0.f;
#pragma unroll
    for (int ci = 0; ci < 2; ++ci) {
#pragma unroll
      for (int r = 0; r < 4; ++r) {
        psi = fmaf(ar[ci][r], acc[ci][nj][r], psi);
        psj = fmaf(aj4[ci][r], acc[ci][nj][r], psj);
      }
      if (node < NN) {
        uint2 pk;
        pk.x = bf16pair(acc[ci][nj][0], acc[ci][nj][1]);
        pk.y = bf16pair(acc[ci][nj][2], acc[ci][nj][3]);
        uint2* dst = (uint2*)(wht + ((size_t)(b * NN + node)) * (CC / 2) + w * 16 + ci * 8 + q * 2);
        *dst = pk;
      }
    }
    psi += __shfl_down(psi, 32);
    psi += __shfl_down(psi, 16);
    psj += __shfl_down(psj, 32);
    psj += __shfl_down(psj, 16);
    if (q == 0) { red[0][w][nj][col] = psi; red[1][w][nj][col] = psj; }
  }
  __syncthreads();

  if (t < TNG) {
    int gn = n0 + t;
    if (gn < NN) {
      int nj = t >> 4, cl = t & 15;
      float s1 = 0.f, s2 = 0.f;
#pragma unroll
      for (int ww = 0; ww < 4; ++ww) { s1 += red[0][ww][nj][cl]; s2 += red[1][ww][nj][cl]; }
      si[b * NN + gn] = s1;
      sj[b * NN + gn] = s2;
    }
  }
}

// ---------------- Gather: XCD-pinned, uint4 row-gathers (4 rows / wave-load) -
__global__ __launch_bounds__(256) void gat_gather(
    const int* __restrict__ ei,      // [2,B,N,K]
    const uint32* __restrict__ wht,  // [B,N,C/2] bf16 pairs
    const float* __restrict__ si,    // [B,N]
    const float* __restrict__ sj,    // [B,N]
    float* __restrict__ out) {       // [B,C,N]
  __shared__ float Am[TNA][KK];        // 1 KB (softmax'd attention weights)
  __shared__ int   jd[TNA][KK];        // 1 KB
  __shared__ float outT2[TNA][OPAD];   // 8.25 KB node-major output tile

  // XCD pinning: xcd = bk%8; XCDs 0-3 -> batch 0, 4-7 -> batch 1.
  const int bk   = blockIdx.x;
  const int xcd  = bk & 7;
  const int b    = xcd >> 2;
  const int slot = (bk >> 3) * 4 + (xcd & 3);
  if (slot >= NN / TNA) return;   // uniform early-out (625 slots/batch, exact)
  const int n0 = slot * TNA;
  const int t  = threadIdx.x;

  const int* eij = ei + b * NN * KK;          // edge_index[0][b] -> j (source)
  const int* eii = ei + (BB + b) * NN * KK;   // edge_index[1][b] -> i (dest)
  const float* sib = si + b * NN;
  const float* sjb = sj + b * NN;

  // Phase A: one edge per thread; softmax over K=16 in-register via
  // 16-lane-group shfl_xor (node nn's 16 edges are lane-contiguous).
  {
    int nn = t >> 4, k = t & 15, gn = n0 + nn;   // gn < NN always (625*16=10000)
    int jj = eij[gn * KK + k];
    int ii = eii[gn * KK + k];
    float v = sib[ii] + sjb[jj];
    float el = (v > 0.f) ? v : 0.2f * v;   // leaky_relu(0.2)
    float mx = el;
#pragma unroll
    for (int d = 1; d < KK; d <<= 1) mx = fmaxf(mx, __shfl_xor(mx, d));
    float ex = __expf(el - mx);
    float s = ex;
#pragma unroll
    for (int d = 1; d < KK; d <<= 1) s += __shfl_xor(s, d);
    Am[nn][k] = ex / s;
    jd[nn][k] = jj;
  }
  __syncthreads();

  // Phase C: lane owns node nn = wave*4 + (lane>>4), channels c16*8..c16*8+7.
  // One uint4 load = 16 B/lane -> a 16-lane quarter covers a full 256 B row,
  // so each wave-load fetches 4 rows. 16 loads/thread, same bytes.
  const int lane = t & 63;
  const int nw   = t >> 6;
  const int nn   = nw * 4 + (lane >> 4);
  const int c16  = lane & 15;
  const uint32* whtb = wht + (size_t)b * NN * (CC / 2);

  uint32 rows[KK]; float wgt[KK];
  {
    uint4 iv[4]; float4 wv[4];
#pragma unroll
    for (int g = 0; g < 4; ++g) {
      iv[g] = ((const uint4*)&jd[nn][0])[g];    // broadcast within quarter
      wv[g] = ((const float4*)&Am[nn][0])[g];
    }
#pragma unroll
    for (int g = 0; g < 4; ++g) {
      rows[4 * g + 0] = iv[g].x; rows[4 * g + 1] = iv[g].y;
      rows[4 * g + 2] = iv[g].z; rows[4 * g + 3] = iv[g].w;
      wgt[4 * g + 0] = wv[g].x;  wgt[4 * g + 1] = wv[g].y;
      wgt[4 * g + 2] = wv[g].z;  wgt[4 * g + 3] = wv[g].w;
    }
  }

  float acc8[8];
#pragma unroll
  for (int r = 0; r < 8; ++r) acc8[r] = 0.f;

  const uint32 lo4 = (uint32)(c16 * 4);   // dword offset of this lane's quad
#pragma unroll
  for (int half = 0; half < 2; ++half) {  // two batches of 8 loads (VGPR cap)
    uint4 v[8];
#pragma unroll
    for (int k = 0; k < 8; ++k)
      v[k] = *(const uint4*)(whtb + rows[half * 8 + k] * (uint32)(CC / 2) + lo4);
#pragma unroll
    for (int k = 0; k < 8; ++k) {
      float wk = wgt[half * 8 + k];
      uint32 dw[4] = {v[k].x, v[k].y, v[k].z, v[k].w};
#pragma unroll
      for (int d = 0; d < 4; ++d) {
        acc8[2 * d]     = fmaf(wk, __uint_as_float(dw[d] << 16), acc8[2 * d]);
        acc8[2 * d + 1] = fmaf(wk, __uint_as_float(dw[d] & 0xffff0000u), acc8[2 * d + 1]);
      }
    }
  }

  // Store lane's 8 contiguous channels: two b128 LDS stores.
  {
    float* orow = &outT2[nn][c16 * 8];
    *(float4*)(orow)     = (float4){acc8[0], acc8[1], acc8[2], acc8[3]};
    *(float4*)(orow + 4) = (float4){acc8[4], acc8[5], acc8[6], acc8[7]};
  }
  __syncthreads();

  // Phase D: coalesced channel-major store (64 B segments per 16 lanes).
  float* outb = out + (size_t)b * CC * NN;
#pragma unroll
  for (int i = 0; i < (CC * TNA) / 256; ++i) {   // 8 iters
    int e = t + i * 256;
    int c = e >> 4, nd = e & 15;
    outb[c * NN + (n0 + nd)] = outT2[nd][c];
  }
}

extern "C" void kernel_launch(void* const* d_in, const int* in_sizes, int n_in,
                              void* d_out, int out_size, void* d_ws, size_t ws_size,
                              hipStream_t stream) {
  const float* x  = (const float*)d_in[0];   // [B,C,N,1]
  const int*   ei = (const int*)d_in[1];     // [2,B,N,K]
  const float* W  = (const float*)d_in[2];   // [C,C]
  const float* a  = (const float*)d_in[3];   // [2C]
  float* out = (float*)d_out;                // [B,C,N,1]

  uint32* wht = (uint32*)d_ws;               // [B*N*C/2] bf16 pairs (5.12 MB)
  float*  si  = (float*)(wht + (size_t)BB * NN * (CC / 2));
  float*  sj  = si + BB * NN;

  dim3 g1((NN + TNG - 1) / TNG, BB);   // 313 x 2, 256 threads
  gat_gemm<<<g1, 256, 0, stream>>>(x, W, a, wht, si, sj);
  // 157 groups * 8 XCD-slots = 1256 blocks -> 628 slots/batch (625 used)
  gat_gather<<<dim3(157 * 8), 256, 0, stream>>>(ei, wht, si, sj, out);
}